// Round 1
// baseline (341.587 us; speedup 1.0000x reference)
//
#include <hip/hip_runtime.h>
#include <cstdint>
#include <cstddef>

#define N_PTS   16384
#define K_CODES 8192
#define DIM     256
#define DECAYF  0.99f
#define OMDF    0.01f
#define EPSF    1e-5f

// output layout (float32, concatenated in reference return order)
#define OFF_ZQ   0
#define OFF_LOSS 4194304
#define OFF_IDX  4194305
#define OFF_W    4210689
#define OFF_CS   6307841
#define OFF_EA   6316033

// scratch parked inside output regions that are written later:
//  zb  = bf16[16384*256] at out+OFF_ZQ            (8 MB, = 128*z)  } z_q region,
//  wb  = bf16[ 8192*256] at out+OFF_ZQ+2097152    (4 MB)           } dead after
//  hen = f32 [ 8192]     at out+OFF_ZQ+3145728    (32 KB)          } k_gemm
//  c1,c2 = u32[64][16384] x2 at out+OFF_W         (8 MB exact fit; dead after
//                                                  k_rescore; k_gather rewrites)
#define ZB_OFF   OFF_ZQ
#define WB_OFF   (OFF_ZQ + 2097152)
#define HEN_OFF  (OFF_ZQ + 3145728)
#define C1_OFF   OFF_W
#define C2_OFF   (OFF_W + 1048576)

typedef __attribute__((ext_vector_type(8))) short bf16x8;
typedef __attribute__((ext_vector_type(4))) float f32x4;

__device__ inline unsigned short f2b(float f) {  // fp32 -> bf16 bits, RNE
    unsigned u = __float_as_uint(f);
    return (unsigned short)((u + 0x7FFFu + ((u >> 16) & 1u)) >> 16);
}

__device__ inline unsigned umaxu(unsigned a, unsigned b) { return a > b ? a : b; }
__device__ inline unsigned uminu(unsigned a, unsigned b) { return a < b ? a : b; }

__device__ inline void gload16(const void* g, void* l) {
    __builtin_amdgcn_global_load_lds(
        (const __attribute__((address_space(1))) unsigned int*)g,
        (__attribute__((address_space(3))) unsigned int*)l, 16, 0, 0);
}

// ---- 1. fp32 -> bf16 (z scaled by 128) + per-point ||z||^2 + hen + cnt zero -
__global__ void k_cvt2(const float* __restrict__ z, short* __restrict__ zb,
                       const float* __restrict__ w, short* __restrict__ wb,
                       float* __restrict__ hen, unsigned* __restrict__ cnt,
                       float* __restrict__ zn2) {
    const int tid = threadIdx.x;
    if (blockIdx.x < N_PTS * DIM / 2048) {
        size_t base = (size_t)(blockIdx.x * 256 + tid) * 8;
        float4 a = *(const float4*)(z + base);
        float4 b = *(const float4*)(z + base + 4);
        bf16x8 o;                                   // zb = 128*z (exact scale)
        o[0] = (short)f2b(128.f * a.x); o[1] = (short)f2b(128.f * a.y);
        o[2] = (short)f2b(128.f * a.z); o[3] = (short)f2b(128.f * a.w);
        o[4] = (short)f2b(128.f * b.x); o[5] = (short)f2b(128.f * b.y);
        o[6] = (short)f2b(128.f * b.z); o[7] = (short)f2b(128.f * b.w);
        *(bf16x8*)(zb + base) = o;
        // per-point ||z||^2 (32 threads per point)
        float s = a.x * a.x + a.y * a.y + a.z * a.z + a.w * a.w
                + b.x * b.x + b.y * b.y + b.z * b.z + b.w * b.w;
        #pragma unroll
        for (int m = 16; m >= 1; m >>= 1) s += __shfl_xor(s, m, 64);
        if ((tid & 31) == 0) zn2[blockIdx.x * 8 + (tid >> 5)] = s;
    } else {
        int blk = blockIdx.x - N_PTS * DIM / 2048;
        size_t base = (size_t)(blk * 256 + tid) * 8;
        float4 a = *(const float4*)(w + base);
        float4 b = *(const float4*)(w + base + 4);
        bf16x8 o;
        o[0] = (short)f2b(a.x); o[1] = (short)f2b(a.y);
        o[2] = (short)f2b(a.z); o[3] = (short)f2b(a.w);
        o[4] = (short)f2b(b.x); o[5] = (short)f2b(b.y);
        o[6] = (short)f2b(b.z); o[7] = (short)f2b(b.w);
        *(bf16x8*)(wb + base) = o;
        float s = a.x * a.x + a.y * a.y + a.z * a.z + a.w * a.w
                + b.x * b.x + b.y * b.y + b.z * b.z + b.w * b.w;
        #pragma unroll
        for (int m = 16; m >= 1; m >>= 1) s += __shfl_xor(s, m, 64);
        if ((tid & 31) == 0) hen[base >> 8] = 0.5f * s;
        int gid = blk * 256 + tid;
        if (gid < K_CODES) cnt[gid] = 0u;
    }
}

// ---- 2. bf16 MFMA GEMM, 256x256 tile, pipelined staging ---------------------
// 8 waves (2M x 4N), per-wave 128x64 output (acc 8x4 f32x4 = 128 regs).
// K=256 in 4 tiles of BK=64, double-buffered LDS (64KB A + 64KB B), stage for
// tile t+1 issued right after the tile-t barrier so the 8 global_load_lds fly
// during the whole tile-t compute. Raw s_barrier + inline vmcnt(0): at the
// barrier, the ONLY outstanding loads are the ones we need -> no over-drain.
// One barrier per 64-K-step (vs 2 in the old 128^2 kernel); L2->LDS staging
// traffic halved (512 MB); MFMA:ds_read = 64:24 per tile.
// Epilogue: per-wave top-2 of its 64-code slice (proven 16x16 pattern), then
// LDS merge of wn-pairs -> c1/c2 with the SAME per-128-code-tile semantics,
// same quantized keys, same accumulation order => bit-identical downstream.
__device__ __forceinline__ void stage_tile(const short* __restrict__ zb,
                                           const short* __restrict__ wb,
                                           int z0, int k0g, int t,
                                           short* Ab, short* Bb,
                                           int wv, int lane) {
    const int sr = lane >> 3;              // row within 8-row segment
    const int chunk = (lane & 7) ^ sr;     // pre-swizzled global k-chunk
    const int koff = t * 64 + chunk * 8;
    #pragma unroll
    for (int i = 0; i < 4; ++i) {
        const int seg = wv * 4 + i;        // 32 segments of 8 rows = 256 rows
        const int row = seg * 8 + sr;
        gload16(zb + (size_t)(z0 + row) * DIM + koff, Ab + seg * 512 + lane * 8);
        gload16(wb + (size_t)(k0g + row) * DIM + koff, Bb + seg * 512 + lane * 8);
    }
}

__global__ __launch_bounds__(512, 2) void k_gemm(const short* __restrict__ zb,
                                                 const short* __restrict__ wb,
                                                 const float* __restrict__ hen,
                                                 unsigned* __restrict__ c1,
                                                 unsigned* __restrict__ c2) {
    __shared__ __align__(16) short As[2][16384];   // 64 KB (256 rows x 64 k) x2
    __shared__ __align__(16) short Bs[2][16384];   // 64 KB
    __shared__ unsigned ldsT[256][8];              // 8 KB merge buffer

    const int tid  = threadIdx.x;
    const int lane = tid & 63;
    const int wv   = tid >> 6;              // 0..7
    const int wm   = wv >> 2;               // 0..1  (M half)
    const int wn   = wv & 3;                // 0..3  (N quarter)
    const int kt    = blockIdx.x & 31;      // ztile-major: 32 kt blocks share A
    const int ztile = blockIdx.x >> 5;      // 0..63
    const int z0 = ztile * 256, k0g = kt * 256;
    const int col = lane & 15;

    f32x4 acc[8][4];
    #pragma unroll
    for (int ni = 0; ni < 4; ni++) {
        float h = 131072.0f - 128.0f * hen[k0g + wn * 64 + ni * 16 + col];
        f32x4 iv = {h, h, h, h};
        #pragma unroll
        for (int mi = 0; mi < 8; mi++) acc[mi][ni] = iv;
    }
    const unsigned invL = (unsigned)(K_CODES - 1 - (k0g + wn * 64 + col));

    stage_tile(zb, wb, z0, k0g, 0, As[0], Bs[0], wv, lane);

    const int ar = (wm * 128 + col) * 64;   // + mi*1024 (shorts)
    const int br = (wn * 64 + col) * 64;    // + ni*1024

    #pragma unroll 1
    for (int t = 0; t < 4; ++t) {
        asm volatile("s_waitcnt vmcnt(0)" ::: "memory");
        __builtin_amdgcn_s_barrier();
        asm volatile("" ::: "memory");
        if (t < 3)
            stage_tile(zb, wb, z0, k0g, t + 1, As[(t + 1) & 1], Bs[(t + 1) & 1], wv, lane);
        const short* Ab = As[t & 1];
        const short* Bb = Bs[t & 1];
        #pragma unroll
        for (int kk = 0; kk < 2; ++kk) {
            const int s8 = ((((kk << 2) + (lane >> 4)) ^ (lane & 7)) << 3);
            bf16x8 b[4];
            #pragma unroll
            for (int ni = 0; ni < 4; ni++)
                b[ni] = *(const bf16x8*)&Bb[br + ni * 1024 + s8];
            #pragma unroll
            for (int mi = 0; mi < 8; mi++) {
                bf16x8 a = *(const bf16x8*)&Ab[ar + mi * 1024 + s8];
                #pragma unroll
                for (int ni = 0; ni < 4; ni++)
                    acc[mi][ni] = __builtin_amdgcn_mfma_f32_16x16x32_bf16(
                        a, b[ni], acc[mi][ni], 0, 0, 0);
            }
        }
    }

    // epilogue: per-wave top-2 of its 64 codes per z-row (keys: q<<13 | invid)
    #pragma unroll
    for (int mi = 0; mi < 8; mi++) {
        #pragma unroll
        for (int r = 0; r < 4; r++) {
            unsigned k4[4];
            #pragma unroll
            for (int ni = 0; ni < 4; ni++) {
                unsigned q = (unsigned)acc[mi][ni][r];
                k4[ni] = (q << 13) | (invL - 16u * ni);
            }
            unsigned p1 = umaxu(k4[0], k4[1]), q1 = uminu(k4[0], k4[1]);
            unsigned p2 = umaxu(k4[2], k4[3]), q2 = uminu(k4[2], k4[3]);
            unsigned t1 = umaxu(p1, p2);
            unsigned t2 = umaxu(uminu(p1, p2), umaxu(q1, q2));
            unsigned m1 = t1;
            #pragma unroll
            for (int m = 8; m >= 1; m >>= 1)
                m1 = umaxu(m1, (unsigned)__shfl_xor((int)m1, m, 64));
            unsigned cc = (t1 == m1) ? t2 : t1;     // keys unique (code id bits)
            #pragma unroll
            for (int m = 8; m >= 1; m >>= 1)
                cc = umaxu(cc, (unsigned)__shfl_xor((int)cc, m, 64));
            if (col == 0) {
                int rowl = wm * 128 + mi * 16 + (lane >> 4) * 4 + r;
                ldsT[rowl][wn * 2]     = m1;
                ldsT[rowl][wn * 2 + 1] = cc;
            }
        }
    }
    __syncthreads();
    // merge wn pairs -> per-128-code-tile top-2 (identical c1/c2 semantics)
    {
        int row = tid & 255, pr = tid >> 8;   // pr 0: codes 0-127, 1: 128-255
        unsigned a0 = ldsT[row][pr * 4 + 0], a1 = ldsT[row][pr * 4 + 1];
        unsigned b0 = ldsT[row][pr * 4 + 2], b1 = ldsT[row][pr * 4 + 3];
        unsigned t1 = umaxu(a0, b0);
        unsigned t2 = umaxu(uminu(a0, b0), umaxu(a1, b1));
        size_t o = (size_t)((kt << 1) + pr) * N_PTS + z0 + row;
        c1[o] = t1;
        c2[o] = t2;
    }
}

// ---- 3. rescore: idx + loss only (no z read, no z_q write, no fast-path w) --
// loss identity: ||z - w||^2 = ||z||^2 - 2*score. Fast path uses the quantized
// key score ((q - 131072)/128, error <= 1/128 + bf16 noise -> ~3e-5 on final
// mean loss). Slow path tracks the winner's fp32 score.
__global__ __launch_bounds__(1024) void k_rescore(
        const float* __restrict__ z, const float* __restrict__ w,
        const unsigned* __restrict__ c1, const unsigned* __restrict__ c2,
        const float* __restrict__ zn2,
        float* __restrict__ out,
        unsigned* __restrict__ cnt, float* __restrict__ lossp) {
    __shared__ unsigned s1[64 * 17], s2[64 * 17];   // 8.5 KB
    const int t  = threadIdx.x;
    const int w0 = blockIdx.x * 16;
    {
        int kt = t >> 4, wo = t & 15;               // 64-B line per 16 threads
        s1[kt * 17 + wo] = c1[(size_t)kt * N_PTS + w0 + wo];
        s2[kt * 17 + wo] = c2[(size_t)kt * N_PTS + w0 + wo];
    }
    __syncthreads();
    const int wv   = t >> 6;       // 0..15 -> wid
    const int lane = t & 63;       // = kt
    const int wid  = w0 + wv;
    unsigned k1 = s1[lane * 17 + wv];
    unsigned k2 = s2[lane * 17 + wv];

    // global best m1 and runner-up m2 over all 128 keys (k1 >= k2 per lane)
    unsigned m1 = k1;
    #pragma unroll
    for (int m = 32; m >= 1; m >>= 1)
        m1 = umaxu(m1, (unsigned)__shfl_xor((int)m1, m, 64));
    unsigned e = (k1 == m1) ? k2 : k1;
    unsigned m2 = e;
    #pragma unroll
    for (int m = 32; m >= 1; m >>= 1)
        m2 = umaxu(m2, (unsigned)__shfl_xor((int)m2, m, 64));

    int idx = K_CODES - 1 - (int)(m1 & 0x1FFFu);
    float scf = ((float)(int)(m1 >> 13) - 131072.0f) * 0.0078125f;

    unsigned qthr = (m1 >> 13) - 96u;     // 0.75 fp32-score window
    if ((m2 >> 13) >= qthr) {             // wave-uniform slow path (~20%)
        unsigned long long best = 0ULL;
        float bsc = 0.f;
        #pragma unroll
        for (int j = 0; j < 2; j++) {
            unsigned cj = j ? k2 : k1;
            unsigned long long mask = __ballot((cj >> 13) >= qthr);
            while (mask) {
                int l = __ffsll((unsigned long long)mask) - 1;
                mask &= mask - 1;
                unsigned cwd = (unsigned)__shfl((int)cj, l, 64);
                int k = K_CODES - 1 - (int)(cwd & 0x1FFFu);
                float4 wr = *(const float4*)(w + (size_t)k * DIM + lane * 4);
                float s = 0.f, h = 0.f;
                {
                    const float* zr = z + (size_t)wid * DIM + lane * 4;
                    float4 zv = *(const float4*)zr;
                    s = zv.x * wr.x + zv.y * wr.y + zv.z * wr.z + zv.w * wr.w;
                    h = wr.x * wr.x + wr.y * wr.y + wr.z * wr.z + wr.w * wr.w;
                }
                #pragma unroll
                for (int m = 32; m >= 1; m >>= 1) {
                    s += __shfl_xor(s, m, 64);
                    h += __shfl_xor(h, m, 64);
                }
                float sc = s - 0.5f * h;
                unsigned u = __float_as_uint(sc);
                u = (u & 0x80000000u) ? ~u : (u | 0x80000000u);
                unsigned long long key = ((unsigned long long)u << 32)
                                       | (unsigned)(K_CODES - 1 - k);
                bool better = key > best;             // wave-uniform
                best = better ? key : best;
                bsc  = better ? sc  : bsc;
            }
        }
        idx = K_CODES - 1 - (int)(unsigned)(best & 0xFFFFFFFFull);
        scf = bsc;
    }

    if (lane == 0) {
        out[OFF_IDX + wid] = (float)idx;
        lossp[wid] = zn2[wid] - 2.0f * scf;
        atomicAdd(cnt + idx, 1u);
    }
}

// ---- 4. single-block: scan + new_cs + n + loss + fill (cursor in LDS) -------
__global__ __launch_bounds__(1024) void k_prefix(const float* __restrict__ csin,
                                                 float* __restrict__ out,
                                                 const unsigned* __restrict__ cnt,
                                                 unsigned* __restrict__ offs,
                                                 unsigned* __restrict__ list,
                                                 const float* __restrict__ lossp,
                                                 float* __restrict__ nval) {
    __shared__ unsigned scur[K_CODES];     // 32 KB LDS cursor
    __shared__ unsigned wtot[16], wbase[16];
    __shared__ float fred[16], fred2[16];
    int t = threadIdx.x, lane = t & 63, wv = t >> 6;
    int base = t * 8;
    unsigned c[8], mysum = 0;
    #pragma unroll
    for (int i = 0; i < 8; i++) { c[i] = cnt[base + i]; mysum += c[i]; }
    unsigned inc = mysum;
    #pragma unroll
    for (int off = 1; off < 64; off <<= 1) {
        unsigned v = (unsigned)__shfl_up((int)inc, off, 64);
        if (lane >= off) inc += v;
    }
    if (lane == 63) wtot[wv] = inc;
    __syncthreads();
    if (t == 0) {
        unsigned r = 0;
        for (int i = 0; i < 16; i++) { wbase[i] = r; r += wtot[i]; }
        offs[K_CODES] = r;
    }
    __syncthreads();
    unsigned my0 = wbase[wv] + inc - mysum;
    float csl = 0.f;
    #pragma unroll
    for (int i = 0; i < 8; i++) {
        offs[base + i] = my0;
        scur[base + i] = my0;
        my0 += c[i];
        float ncs = DECAYF * csin[base + i] + OMDF * (float)c[i];
        out[OFF_CS + base + i] = ncs;
        csl += ncs;
    }
    #pragma unroll
    for (int m = 32; m >= 1; m >>= 1) csl += __shfl_xor(csl, m, 64);
    if (lane == 0) fred[wv] = csl;
    float lp = 0.f;
    #pragma unroll
    for (int i = 0; i < 16; i++) lp += lossp[t + i * 1024];
    #pragma unroll
    for (int m = 32; m >= 1; m >>= 1) lp += __shfl_xor(lp, m, 64);
    if (lane == 0) fred2[wv] = lp;
    __syncthreads();
    if (t == 0) {
        float n = 0.f, L = 0.f;
        for (int i = 0; i < 16; i++) { n += fred[i]; L += fred2[i]; }
        *nval = n;
        out[OFF_LOSS] = L * (1.0f / ((float)N_PTS * DIM));
    }
    // fill phase: LDS-atomic cursors, scattered list writes
    for (int i = t; i < N_PTS; i += 1024) {
        int idx = (int)out[OFF_IDX + i];
        unsigned pos = atomicAdd(&scur[idx], 1u);
        list[pos] = (unsigned)i;
    }
}

// ---- 5. per-code gather: z_q scatter + new_ea + new_weight (no atomics) -----
__global__ void k_gather(const float* __restrict__ z, const float* __restrict__ ea,
                         const float* __restrict__ w,
                         float* __restrict__ out,
                         const unsigned* __restrict__ offs,
                         const unsigned* __restrict__ list,
                         const float* __restrict__ nval) {
    int k = blockIdx.x, lane = threadIdx.x;
    unsigned beg = offs[k], end = offs[k + 1];
    float4 wv = *(const float4*)(w + (size_t)k * DIM + lane * 4);
    float4 acc = {0.f, 0.f, 0.f, 0.f};
    for (unsigned p = beg; p < end; ++p) {
        unsigned i = list[p];
        float4 zv = *(const float4*)(z + (size_t)i * DIM + lane * 4);
        acc.x += zv.x; acc.y += zv.y; acc.z += zv.z; acc.w += zv.w;
        *(float4*)(out + OFF_ZQ + (size_t)i * DIM + lane * 4) = wv;  // z_q = w[idx]
    }
    float4 e = *(const float4*)(ea + (size_t)k * DIM + lane * 4);
    e.x = DECAYF * e.x + OMDF * acc.x;
    e.y = DECAYF * e.y + OMDF * acc.y;
    e.z = DECAYF * e.z + OMDF * acc.z;
    e.w = DECAYF * e.w + OMDF * acc.w;
    *(float4*)(out + OFF_EA + (size_t)k * DIM + lane * 4) = e;

    float cs = out[OFF_CS + k];
    float n  = *nval;
    float inv = 1.f / ((cs + EPSF) / (n + (float)K_CODES * EPSF) * n);
    float4 wr = {e.x * inv, e.y * inv, e.z * inv, e.w * inv};
    *(float4*)(out + OFF_W + (size_t)k * DIM + lane * 4) = wr;
}

extern "C" void kernel_launch(void* const* d_in, const int* in_sizes, int n_in,
                              void* d_out, int out_size, void* d_ws, size_t ws_size,
                              hipStream_t stream) {
    const float* z  = (const float*)d_in[0];
    const float* w  = (const float*)d_in[1];
    const float* cs = (const float*)d_in[2];
    const float* ea = (const float*)d_in[3];
    float* out = (float*)d_out;

    short*    zb  = (short*)(out + ZB_OFF);
    short*    wb  = (short*)(out + WB_OFF);
    float*    hen = out + HEN_OFF;
    unsigned* c1  = (unsigned*)(out + C1_OFF);
    unsigned* c2  = (unsigned*)(out + C2_OFF);

    // small scratch in d_ws (~262 KB)
    unsigned* cnt   = (unsigned*)d_ws;        // 8192
    unsigned* offs  = cnt + 8192;             // 8193 (padded to 8200)
    unsigned* list  = offs + 8200;            // 16384
    float*    lossp = (float*)(list + 16384); // 16384
    float*    nval  = lossp + 16384;          // 1
    float*    zn2   = nval + 1;               // 16384

    hipLaunchKernelGGL(k_cvt2,    dim3((N_PTS + K_CODES) * DIM / 2048), dim3(256), 0, stream,
                       z, zb, w, wb, hen, cnt, zn2);
    hipLaunchKernelGGL(k_gemm,    dim3((N_PTS / 256) * (K_CODES / 256)), dim3(512), 0, stream,
                       zb, wb, hen, c1, c2);
    hipLaunchKernelGGL(k_rescore, dim3(N_PTS / 16),           dim3(1024), 0, stream,
                       z, w, c1, c2, zn2, out, cnt, lossp);
    hipLaunchKernelGGL(k_prefix,  dim3(1),                    dim3(1024), 0, stream,
                       cs, out, cnt, offs, list, lossp, nval);
    hipLaunchKernelGGL(k_gather,  dim3(K_CODES),              dim3(64), 0, stream,
                       z, ea, w, out, offs, list, nval);
}

// Round 2
// 333.711 us; speedup vs baseline: 1.0236x; 1.0236x over previous
//
#include <hip/hip_runtime.h>
#include <cstdint>
#include <cstddef>

#define N_PTS   16384
#define K_CODES 8192
#define DIM     256
#define DECAYF  0.99f
#define OMDF    0.01f
#define EPSF    1e-5f

// output layout (float32, concatenated in reference return order)
#define OFF_ZQ   0
#define OFF_LOSS 4194304
#define OFF_IDX  4194305
#define OFF_W    4210689
#define OFF_CS   6307841
#define OFF_EA   6316033

// scratch parked inside output regions that are written later:
//  zb  = bf16[16384*256] at out+OFF_ZQ            (8 MB, = 128*z)  } z_q region,
//  wb  = bf16[ 8192*256] at out+OFF_ZQ+2097152    (4 MB)           } dead after
//  hen = f32 [ 8192]     at out+OFF_ZQ+3145728    (32 KB)          } k_gemm
//  c1,c2 = u32[64][16384] x2 at out+OFF_W         (8 MB exact fit; dead after
//                                                  k_rescore; k_gather rewrites)
#define ZB_OFF   OFF_ZQ
#define WB_OFF   (OFF_ZQ + 2097152)
#define HEN_OFF  (OFF_ZQ + 3145728)
#define C1_OFF   OFF_W
#define C2_OFF   (OFF_W + 1048576)

typedef __attribute__((ext_vector_type(8))) short bf16x8;
typedef __attribute__((ext_vector_type(4))) float f32x4;

__device__ inline unsigned short f2b(float f) {  // fp32 -> bf16 bits, RNE
    unsigned u = __float_as_uint(f);
    return (unsigned short)((u + 0x7FFFu + ((u >> 16) & 1u)) >> 16);
}

__device__ inline unsigned umaxu(unsigned a, unsigned b) { return a > b ? a : b; }
__device__ inline unsigned uminu(unsigned a, unsigned b) { return a < b ? a : b; }

__device__ inline void gload16(const void* g, void* l) {
    __builtin_amdgcn_global_load_lds(
        (const __attribute__((address_space(1))) unsigned int*)g,
        (__attribute__((address_space(3))) unsigned int*)l, 16, 0, 0);
}

// ---- 1. fp32 -> bf16 (z scaled by 128) + per-point ||z||^2 + hen + cnt zero -
__global__ void k_cvt2(const float* __restrict__ z, short* __restrict__ zb,
                       const float* __restrict__ w, short* __restrict__ wb,
                       float* __restrict__ hen, unsigned* __restrict__ cnt,
                       float* __restrict__ zn2) {
    const int tid = threadIdx.x;
    if (blockIdx.x < N_PTS * DIM / 2048) {
        size_t base = (size_t)(blockIdx.x * 256 + tid) * 8;
        float4 a = *(const float4*)(z + base);
        float4 b = *(const float4*)(z + base + 4);
        bf16x8 o;                                   // zb = 128*z (exact scale)
        o[0] = (short)f2b(128.f * a.x); o[1] = (short)f2b(128.f * a.y);
        o[2] = (short)f2b(128.f * a.z); o[3] = (short)f2b(128.f * a.w);
        o[4] = (short)f2b(128.f * b.x); o[5] = (short)f2b(128.f * b.y);
        o[6] = (short)f2b(128.f * b.z); o[7] = (short)f2b(128.f * b.w);
        *(bf16x8*)(zb + base) = o;
        // per-point ||z||^2 (32 threads per point)
        float s = a.x * a.x + a.y * a.y + a.z * a.z + a.w * a.w
                + b.x * b.x + b.y * b.y + b.z * b.z + b.w * b.w;
        #pragma unroll
        for (int m = 16; m >= 1; m >>= 1) s += __shfl_xor(s, m, 64);
        if ((tid & 31) == 0) zn2[blockIdx.x * 8 + (tid >> 5)] = s;
    } else {
        int blk = blockIdx.x - N_PTS * DIM / 2048;
        size_t base = (size_t)(blk * 256 + tid) * 8;
        float4 a = *(const float4*)(w + base);
        float4 b = *(const float4*)(w + base + 4);
        bf16x8 o;
        o[0] = (short)f2b(a.x); o[1] = (short)f2b(a.y);
        o[2] = (short)f2b(a.z); o[3] = (short)f2b(a.w);
        o[4] = (short)f2b(b.x); o[5] = (short)f2b(b.y);
        o[6] = (short)f2b(b.z); o[7] = (short)f2b(b.w);
        *(bf16x8*)(wb + base) = o;
        float s = a.x * a.x + a.y * a.y + a.z * a.z + a.w * a.w
                + b.x * b.x + b.y * b.y + b.z * b.z + b.w * b.w;
        #pragma unroll
        for (int m = 16; m >= 1; m >>= 1) s += __shfl_xor(s, m, 64);
        if ((tid & 31) == 0) hen[base >> 8] = 0.5f * s;
        int gid = blk * 256 + tid;
        if (gid < K_CODES) cnt[gid] = 0u;
    }
}

// ---- 2. bf16 MFMA GEMM, 256x256 tile, 8-phase (T3+T4+T5) schedule -----------
// Geometry: 8 waves (2M x 4N), per-wave 128x64 output, acc[8][4] f32x4.
// K=256 = 4 K-steps of BK=64, double-buffered LDS (2 x 32KB A + 2 x 32KB B).
// Per K-step: 4 phases; phase p = { ds_read a-frags (mi 2p,2p+1) ||
//   stage-issue half-tiles of K-step t+1 (p0: A halves, p1: B halves) ->
//   s_barrier -> lgkmcnt(0) -> sched_barrier -> setprio(1) -> 16 MFMA ->
//   setprio(0) -> s_barrier }. b-frags (8) read once at phase 0, held in regs
//   -> total ds_read_b128 stays minimal (24/wave/K-step).
// K-step boundary = __syncthreads(): at that point the ONLY in-flight vmem
// ops are the stages for buf[t&1] (issued >=2 phases earlier, latency hidden
// under MFMA) -> drain == exact counted wait, and cross-wave LDS validity is
// guaranteed by the barrier's full fence. No race window: buf[(t+1)&1]'s last
// readers completed (per-wave lgkmcnt(0)) before the boundary.
// Epilogue identical to proven round-1 code; merge buffer overlays As[0].
__device__ __forceinline__ void stage_half(const short* __restrict__ src,
                                           int row0, int t, short* lds,
                                           int wv, int lane) {
    const int sr = lane >> 3;              // row within 8-row segment
    const int chunk = (lane & 7) ^ sr;     // pre-swizzled global k-chunk
    const int koff = t * 64 + chunk * 8;
    #pragma unroll
    for (int i = 0; i < 2; ++i) {
        const int seg = wv * 2 + i;        // 16 segments of 8 rows = 128 rows
        const int row = seg * 8 + sr;
        gload16(src + (size_t)(row0 + row) * DIM + koff, lds + seg * 512 + lane * 8);
    }
}

__global__ __launch_bounds__(512, 2) void k_gemm(const short* __restrict__ zb,
                                                 const short* __restrict__ wb,
                                                 const float* __restrict__ hen,
                                                 unsigned* __restrict__ c1,
                                                 unsigned* __restrict__ c2) {
    __shared__ __align__(16) short As[2][16384];   // 64 KB (256 rows x 64 k) x2
    __shared__ __align__(16) short Bs[2][16384];   // 64 KB

    const int tid  = threadIdx.x;
    const int lane = tid & 63;
    const int wv   = tid >> 6;              // 0..7
    const int wm   = wv >> 2;               // 0..1  (M half)
    const int wn   = wv & 3;                // 0..3  (N quarter)
    const int kt    = blockIdx.x & 31;      // ztile-major: 32 kt blocks share A
    const int ztile = blockIdx.x >> 5;      // 0..63
    const int z0 = ztile * 256, k0g = kt * 256;
    const int col = lane & 15;
    const int hi  = lane >> 4;
    const int x7  = lane & 7;
    const int s8_0 = (((0 << 2) + hi) ^ x7) << 3;   // de-swizzle pos, kk=0
    const int s8_1 = (((1 << 2) + hi) ^ x7) << 3;   // de-swizzle pos, kk=1

    f32x4 acc[8][4];
    #pragma unroll
    for (int ni = 0; ni < 4; ni++) {
        float h = 131072.0f - 128.0f * hen[k0g + wn * 64 + ni * 16 + col];
        f32x4 iv = {h, h, h, h};
        #pragma unroll
        for (int mi = 0; mi < 8; mi++) acc[mi][ni] = iv;
    }
    const unsigned invL = (unsigned)(K_CODES - 1 - (k0g + wn * 64 + col));

    // prologue: stage all 4 half-tiles of K-step 0 into buffer 0
    stage_half(zb, z0,        0, &As[0][0],    wv, lane);
    stage_half(zb, z0 + 128,  0, &As[0][8192], wv, lane);
    stage_half(wb, k0g,       0, &Bs[0][0],    wv, lane);
    stage_half(wb, k0g + 128, 0, &Bs[0][8192], wv, lane);

    const int arow = (wm * 128 + col) * 64;   // + mi*1024 + s8 (shorts)
    const int brow = (wn * 64 + col) * 64;    // + ni*1024 + s8

#define GPHASE(P, STG)                                                         \
    {                                                                          \
        bf16x8 a00 = *(const bf16x8*)&Ab[arow + (2*(P)+0) * 1024 + s8_0];      \
        bf16x8 a01 = *(const bf16x8*)&Ab[arow + (2*(P)+0) * 1024 + s8_1];      \
        bf16x8 a10 = *(const bf16x8*)&Ab[arow + (2*(P)+1) * 1024 + s8_0];      \
        bf16x8 a11 = *(const bf16x8*)&Ab[arow + (2*(P)+1) * 1024 + s8_1];      \
        STG;                                                                   \
        __builtin_amdgcn_s_barrier();                                          \
        asm volatile("s_waitcnt lgkmcnt(0)" ::: "memory");                     \
        __builtin_amdgcn_sched_barrier(0);                                     \
        __builtin_amdgcn_s_setprio(1);                                         \
        _Pragma("unroll")                                                      \
        for (int ni = 0; ni < 4; ++ni)                                         \
            acc[2*(P)+0][ni] = __builtin_amdgcn_mfma_f32_16x16x32_bf16(        \
                a00, b[ni][0], acc[2*(P)+0][ni], 0, 0, 0);                     \
        _Pragma("unroll")                                                      \
        for (int ni = 0; ni < 4; ++ni)                                         \
            acc[2*(P)+1][ni] = __builtin_amdgcn_mfma_f32_16x16x32_bf16(        \
                a10, b[ni][0], acc[2*(P)+1][ni], 0, 0, 0);                     \
        _Pragma("unroll")                                                      \
        for (int ni = 0; ni < 4; ++ni)                                         \
            acc[2*(P)+0][ni] = __builtin_amdgcn_mfma_f32_16x16x32_bf16(        \
                a01, b[ni][1], acc[2*(P)+0][ni], 0, 0, 0);                     \
        _Pragma("unroll")                                                      \
        for (int ni = 0; ni < 4; ++ni)                                         \
            acc[2*(P)+1][ni] = __builtin_amdgcn_mfma_f32_16x16x32_bf16(        \
                a11, b[ni][1], acc[2*(P)+1][ni], 0, 0, 0);                     \
        __builtin_amdgcn_s_setprio(0);                                         \
        __builtin_amdgcn_s_barrier();                                          \
    }

    #pragma unroll
    for (int t = 0; t < 4; ++t) {
        const short* Ab = As[t & 1];
        const short* Bb = Bs[t & 1];
        short* An = (short*)As[(t + 1) & 1];
        short* Bn = (short*)Bs[(t + 1) & 1];
        __syncthreads();   // K-step boundary: exact drain of buf[t&1] stages

        // b-frags for the whole K-step (8 x ds_read_b128, held in registers)
        bf16x8 b[4][2];
        #pragma unroll
        for (int ni = 0; ni < 4; ++ni) {
            b[ni][0] = *(const bf16x8*)&Bb[brow + ni * 1024 + s8_0];
            b[ni][1] = *(const bf16x8*)&Bb[brow + ni * 1024 + s8_1];
        }
        GPHASE(0, if (t < 3) { stage_half(zb, z0,        t + 1, An,        wv, lane);
                               stage_half(zb, z0 + 128,  t + 1, An + 8192, wv, lane); })
        GPHASE(1, if (t < 3) { stage_half(wb, k0g,       t + 1, Bn,        wv, lane);
                               stage_half(wb, k0g + 128, t + 1, Bn + 8192, wv, lane); })
        GPHASE(2, )
        GPHASE(3, )
    }
#undef GPHASE

    // epilogue: per-wave top-2 of its 64 codes per z-row (keys: q<<13 | invid)
    unsigned (*ldsT)[8] = (unsigned (*)[8])(&As[0][0]);   // 8 KB overlay
    #pragma unroll
    for (int mi = 0; mi < 8; mi++) {
        #pragma unroll
        for (int r = 0; r < 4; r++) {
            unsigned k4[4];
            #pragma unroll
            for (int ni = 0; ni < 4; ni++) {
                unsigned q = (unsigned)acc[mi][ni][r];
                k4[ni] = (q << 13) | (invL - 16u * ni);
            }
            unsigned p1 = umaxu(k4[0], k4[1]), q1 = uminu(k4[0], k4[1]);
            unsigned p2 = umaxu(k4[2], k4[3]), q2 = uminu(k4[2], k4[3]);
            unsigned t1 = umaxu(p1, p2);
            unsigned t2 = umaxu(uminu(p1, p2), umaxu(q1, q2));
            unsigned m1 = t1;
            #pragma unroll
            for (int m = 8; m >= 1; m >>= 1)
                m1 = umaxu(m1, (unsigned)__shfl_xor((int)m1, m, 64));
            unsigned cc = (t1 == m1) ? t2 : t1;     // keys unique (code id bits)
            #pragma unroll
            for (int m = 8; m >= 1; m >>= 1)
                cc = umaxu(cc, (unsigned)__shfl_xor((int)cc, m, 64));
            if (col == 0) {
                int rowl = wm * 128 + mi * 16 + (lane >> 4) * 4 + r;
                ldsT[rowl][wn * 2]     = m1;
                ldsT[rowl][wn * 2 + 1] = cc;
            }
        }
    }
    __syncthreads();
    // merge wn pairs -> per-128-code-tile top-2 (identical c1/c2 semantics)
    {
        int row = tid & 255, pr = tid >> 8;   // pr 0: codes 0-127, 1: 128-255
        unsigned a0 = ldsT[row][pr * 4 + 0], a1 = ldsT[row][pr * 4 + 1];
        unsigned b0 = ldsT[row][pr * 4 + 2], b1 = ldsT[row][pr * 4 + 3];
        unsigned t1 = umaxu(a0, b0);
        unsigned t2 = umaxu(uminu(a0, b0), umaxu(a1, b1));
        size_t o = (size_t)((kt << 1) + pr) * N_PTS + z0 + row;
        c1[o] = t1;
        c2[o] = t2;
    }
}

// ---- 3. rescore: idx + loss only (no z read, no z_q write, no fast-path w) --
// loss identity: ||z - w||^2 = ||z||^2 - 2*score. Fast path uses the quantized
// key score ((q - 131072)/128, error <= 1/128 + bf16 noise -> ~3e-5 on final
// mean loss). Slow path tracks the winner's fp32 score.
__global__ __launch_bounds__(1024) void k_rescore(
        const float* __restrict__ z, const float* __restrict__ w,
        const unsigned* __restrict__ c1, const unsigned* __restrict__ c2,
        const float* __restrict__ zn2,
        float* __restrict__ out,
        unsigned* __restrict__ cnt, float* __restrict__ lossp) {
    __shared__ unsigned s1[64 * 17], s2[64 * 17];   // 8.5 KB
    const int t  = threadIdx.x;
    const int w0 = blockIdx.x * 16;
    {
        int kt = t >> 4, wo = t & 15;               // 64-B line per 16 threads
        s1[kt * 17 + wo] = c1[(size_t)kt * N_PTS + w0 + wo];
        s2[kt * 17 + wo] = c2[(size_t)kt * N_PTS + w0 + wo];
    }
    __syncthreads();
    const int wv   = t >> 6;       // 0..15 -> wid
    const int lane = t & 63;       // = kt
    const int wid  = w0 + wv;
    unsigned k1 = s1[lane * 17 + wv];
    unsigned k2 = s2[lane * 17 + wv];

    // global best m1 and runner-up m2 over all 128 keys (k1 >= k2 per lane)
    unsigned m1 = k1;
    #pragma unroll
    for (int m = 32; m >= 1; m >>= 1)
        m1 = umaxu(m1, (unsigned)__shfl_xor((int)m1, m, 64));
    unsigned e = (k1 == m1) ? k2 : k1;
    unsigned m2 = e;
    #pragma unroll
    for (int m = 32; m >= 1; m >>= 1)
        m2 = umaxu(m2, (unsigned)__shfl_xor((int)m2, m, 64));

    int idx = K_CODES - 1 - (int)(m1 & 0x1FFFu);
    float scf = ((float)(int)(m1 >> 13) - 131072.0f) * 0.0078125f;

    unsigned qthr = (m1 >> 13) - 96u;     // 0.75 fp32-score window
    if ((m2 >> 13) >= qthr) {             // wave-uniform slow path (~20%)
        unsigned long long best = 0ULL;
        float bsc = 0.f;
        #pragma unroll
        for (int j = 0; j < 2; j++) {
            unsigned cj = j ? k2 : k1;
            unsigned long long mask = __ballot((cj >> 13) >= qthr);
            while (mask) {
                int l = __ffsll((unsigned long long)mask) - 1;
                mask &= mask - 1;
                unsigned cwd = (unsigned)__shfl((int)cj, l, 64);
                int k = K_CODES - 1 - (int)(cwd & 0x1FFFu);
                float4 wr = *(const float4*)(w + (size_t)k * DIM + lane * 4);
                float s = 0.f, h = 0.f;
                {
                    const float* zr = z + (size_t)wid * DIM + lane * 4;
                    float4 zv = *(const float4*)zr;
                    s = zv.x * wr.x + zv.y * wr.y + zv.z * wr.z + zv.w * wr.w;
                    h = wr.x * wr.x + wr.y * wr.y + wr.z * wr.z + wr.w * wr.w;
                }
                #pragma unroll
                for (int m = 32; m >= 1; m >>= 1) {
                    s += __shfl_xor(s, m, 64);
                    h += __shfl_xor(h, m, 64);
                }
                float sc = s - 0.5f * h;
                unsigned u = __float_as_uint(sc);
                u = (u & 0x80000000u) ? ~u : (u | 0x80000000u);
                unsigned long long key = ((unsigned long long)u << 32)
                                       | (unsigned)(K_CODES - 1 - k);
                bool better = key > best;             // wave-uniform
                best = better ? key : best;
                bsc  = better ? sc  : bsc;
            }
        }
        idx = K_CODES - 1 - (int)(unsigned)(best & 0xFFFFFFFFull);
        scf = bsc;
    }

    if (lane == 0) {
        out[OFF_IDX + wid] = (float)idx;
        lossp[wid] = zn2[wid] - 2.0f * scf;
        atomicAdd(cnt + idx, 1u);
    }
}

// ---- 4. single-block: scan + new_cs + n + loss + fill (cursor in LDS) -------
__global__ __launch_bounds__(1024) void k_prefix(const float* __restrict__ csin,
                                                 float* __restrict__ out,
                                                 const unsigned* __restrict__ cnt,
                                                 unsigned* __restrict__ offs,
                                                 unsigned* __restrict__ list,
                                                 const float* __restrict__ lossp,
                                                 float* __restrict__ nval) {
    __shared__ unsigned scur[K_CODES];     // 32 KB LDS cursor
    __shared__ unsigned wtot[16], wbase[16];
    __shared__ float fred[16], fred2[16];
    int t = threadIdx.x, lane = t & 63, wv = t >> 6;
    int base = t * 8;
    unsigned c[8], mysum = 0;
    #pragma unroll
    for (int i = 0; i < 8; i++) { c[i] = cnt[base + i]; mysum += c[i]; }
    unsigned inc = mysum;
    #pragma unroll
    for (int off = 1; off < 64; off <<= 1) {
        unsigned v = (unsigned)__shfl_up((int)inc, off, 64);
        if (lane >= off) inc += v;
    }
    if (lane == 63) wtot[wv] = inc;
    __syncthreads();
    if (t == 0) {
        unsigned r = 0;
        for (int i = 0; i < 16; i++) { wbase[i] = r; r += wtot[i]; }
        offs[K_CODES] = r;
    }
    __syncthreads();
    unsigned my0 = wbase[wv] + inc - mysum;
    float csl = 0.f;
    #pragma unroll
    for (int i = 0; i < 8; i++) {
        offs[base + i] = my0;
        scur[base + i] = my0;
        my0 += c[i];
        float ncs = DECAYF * csin[base + i] + OMDF * (float)c[i];
        out[OFF_CS + base + i] = ncs;
        csl += ncs;
    }
    #pragma unroll
    for (int m = 32; m >= 1; m >>= 1) csl += __shfl_xor(csl, m, 64);
    if (lane == 0) fred[wv] = csl;
    float lp = 0.f;
    #pragma unroll
    for (int i = 0; i < 16; i++) lp += lossp[t + i * 1024];
    #pragma unroll
    for (int m = 32; m >= 1; m >>= 1) lp += __shfl_xor(lp, m, 64);
    if (lane == 0) fred2[wv] = lp;
    __syncthreads();
    if (t == 0) {
        float n = 0.f, L = 0.f;
        for (int i = 0; i < 16; i++) { n += fred[i]; L += fred2[i]; }
        *nval = n;
        out[OFF_LOSS] = L * (1.0f / ((float)N_PTS * DIM));
    }
    // fill phase: LDS-atomic cursors, scattered list writes
    for (int i = t; i < N_PTS; i += 1024) {
        int idx = (int)out[OFF_IDX + i];
        unsigned pos = atomicAdd(&scur[idx], 1u);
        list[pos] = (unsigned)i;
    }
}

// ---- 5. per-code gather: z_q scatter + new_ea + new_weight (no atomics) -----
__global__ void k_gather(const float* __restrict__ z, const float* __restrict__ ea,
                         const float* __restrict__ w,
                         float* __restrict__ out,
                         const unsigned* __restrict__ offs,
                         const unsigned* __restrict__ list,
                         const float* __restrict__ nval) {
    int k = blockIdx.x, lane = threadIdx.x;
    unsigned beg = offs[k], end = offs[k + 1];
    float4 wv = *(const float4*)(w + (size_t)k * DIM + lane * 4);
    float4 acc = {0.f, 0.f, 0.f, 0.f};
    for (unsigned p = beg; p < end; ++p) {
        unsigned i = list[p];
        float4 zv = *(const float4*)(z + (size_t)i * DIM + lane * 4);
        acc.x += zv.x; acc.y += zv.y; acc.z += zv.z; acc.w += zv.w;
        *(float4*)(out + OFF_ZQ + (size_t)i * DIM + lane * 4) = wv;  // z_q = w[idx]
    }
    float4 e = *(const float4*)(ea + (size_t)k * DIM + lane * 4);
    e.x = DECAYF * e.x + OMDF * acc.x;
    e.y = DECAYF * e.y + OMDF * acc.y;
    e.z = DECAYF * e.z + OMDF * acc.z;
    e.w = DECAYF * e.w + OMDF * acc.w;
    *(float4*)(out + OFF_EA + (size_t)k * DIM + lane * 4) = e;

    float cs = out[OFF_CS + k];
    float n  = *nval;
    float inv = 1.f / ((cs + EPSF) / (n + (float)K_CODES * EPSF) * n);
    float4 wr = {e.x * inv, e.y * inv, e.z * inv, e.w * inv};
    *(float4*)(out + OFF_W + (size_t)k * DIM + lane * 4) = wr;
}

extern "C" void kernel_launch(void* const* d_in, const int* in_sizes, int n_in,
                              void* d_out, int out_size, void* d_ws, size_t ws_size,
                              hipStream_t stream) {
    const float* z  = (const float*)d_in[0];
    const float* w  = (const float*)d_in[1];
    const float* cs = (const float*)d_in[2];
    const float* ea = (const float*)d_in[3];
    float* out = (float*)d_out;

    short*    zb  = (short*)(out + ZB_OFF);
    short*    wb  = (short*)(out + WB_OFF);
    float*    hen = out + HEN_OFF;
    unsigned* c1  = (unsigned*)(out + C1_OFF);
    unsigned* c2  = (unsigned*)(out + C2_OFF);

    // small scratch in d_ws (~262 KB)
    unsigned* cnt   = (unsigned*)d_ws;        // 8192
    unsigned* offs  = cnt + 8192;             // 8193 (padded to 8200)
    unsigned* list  = offs + 8200;            // 16384
    float*    lossp = (float*)(list + 16384); // 16384
    float*    nval  = lossp + 16384;          // 1
    float*    zn2   = nval + 1;               // 16384

    hipLaunchKernelGGL(k_cvt2,    dim3((N_PTS + K_CODES) * DIM / 2048), dim3(256), 0, stream,
                       z, zb, w, wb, hen, cnt, zn2);
    hipLaunchKernelGGL(k_gemm,    dim3((N_PTS / 256) * (K_CODES / 256)), dim3(512), 0, stream,
                       zb, wb, hen, c1, c2);
    hipLaunchKernelGGL(k_rescore, dim3(N_PTS / 16),           dim3(1024), 0, stream,
                       z, w, c1, c2, zn2, out, cnt, lossp);
    hipLaunchKernelGGL(k_prefix,  dim3(1),                    dim3(1024), 0, stream,
                       cs, out, cnt, offs, list, lossp, nval);
    hipLaunchKernelGGL(k_gather,  dim3(K_CODES),              dim3(64), 0, stream,
                       z, ea, w, out, offs, list, nval);
}

// Round 3
// 306.061 us; speedup vs baseline: 1.1161x; 1.0903x over previous
//
#include <hip/hip_runtime.h>
#include <cstdint>
#include <cstddef>

#define N_PTS   16384
#define K_CODES 8192
#define DIM     256
#define DECAYF  0.99f
#define OMDF    0.01f
#define EPSF    1e-5f

// output layout (float32, concatenated in reference return order)
#define OFF_ZQ   0
#define OFF_LOSS 4194304
#define OFF_IDX  4194305
#define OFF_W    4210689
#define OFF_CS   6307841
#define OFF_EA   6316033

// scratch parked inside output regions that are written later:
//  zb  = bf16[16384*256] at out+OFF_ZQ            (8 MB, = 128*z)  } z_q region,
//  wb  = bf16[ 8192*256] at out+OFF_ZQ+2097152    (4 MB)           } dead after
//  hen = f32 [ 8192]     at out+OFF_ZQ+3145728    (32 KB)          } k_gemm
//  c1,c2 = u32[64][16384] x2 at out+OFF_W         (8 MB exact fit; dead after
//                                                  k_rescore; k_gather rewrites)
#define ZB_OFF   OFF_ZQ
#define WB_OFF   (OFF_ZQ + 2097152)
#define HEN_OFF  (OFF_ZQ + 3145728)
#define C1_OFF   OFF_W
#define C2_OFF   (OFF_W + 1048576)

typedef __attribute__((ext_vector_type(8))) short bf16x8;
typedef __attribute__((ext_vector_type(4))) float f32x4;

__device__ inline unsigned short f2b(float f) {  // fp32 -> bf16 bits, RNE
    unsigned u = __float_as_uint(f);
    return (unsigned short)((u + 0x7FFFu + ((u >> 16) & 1u)) >> 16);
}

__device__ inline unsigned umaxu(unsigned a, unsigned b) { return a > b ? a : b; }
__device__ inline unsigned uminu(unsigned a, unsigned b) { return a < b ? a : b; }

__device__ inline void gload16(const void* g, void* l) {
    __builtin_amdgcn_global_load_lds(
        (const __attribute__((address_space(1))) unsigned int*)g,
        (__attribute__((address_space(3))) unsigned int*)l, 16, 0, 0);
}

// ---- 1. fp32 -> bf16 (z scaled by 128) + per-point ||z||^2 + hen + cnt zero -
__global__ void k_cvt2(const float* __restrict__ z, short* __restrict__ zb,
                       const float* __restrict__ w, short* __restrict__ wb,
                       float* __restrict__ hen, unsigned* __restrict__ cnt,
                       float* __restrict__ zn2) {
    const int tid = threadIdx.x;
    if (blockIdx.x < N_PTS * DIM / 2048) {
        size_t base = (size_t)(blockIdx.x * 256 + tid) * 8;
        float4 a = *(const float4*)(z + base);
        float4 b = *(const float4*)(z + base + 4);
        bf16x8 o;                                   // zb = 128*z (exact scale)
        o[0] = (short)f2b(128.f * a.x); o[1] = (short)f2b(128.f * a.y);
        o[2] = (short)f2b(128.f * a.z); o[3] = (short)f2b(128.f * a.w);
        o[4] = (short)f2b(128.f * b.x); o[5] = (short)f2b(128.f * b.y);
        o[6] = (short)f2b(128.f * b.z); o[7] = (short)f2b(128.f * b.w);
        *(bf16x8*)(zb + base) = o;
        // per-point ||z||^2 (32 threads per point)
        float s = a.x * a.x + a.y * a.y + a.z * a.z + a.w * a.w
                + b.x * b.x + b.y * b.y + b.z * b.z + b.w * b.w;
        #pragma unroll
        for (int m = 16; m >= 1; m >>= 1) s += __shfl_xor(s, m, 64);
        if ((tid & 31) == 0) zn2[blockIdx.x * 8 + (tid >> 5)] = s;
    } else {
        int blk = blockIdx.x - N_PTS * DIM / 2048;
        size_t base = (size_t)(blk * 256 + tid) * 8;
        float4 a = *(const float4*)(w + base);
        float4 b = *(const float4*)(w + base + 4);
        bf16x8 o;
        o[0] = (short)f2b(a.x); o[1] = (short)f2b(a.y);
        o[2] = (short)f2b(a.z); o[3] = (short)f2b(a.w);
        o[4] = (short)f2b(b.x); o[5] = (short)f2b(b.y);
        o[6] = (short)f2b(b.z); o[7] = (short)f2b(b.w);
        *(bf16x8*)(wb + base) = o;
        float s = a.x * a.x + a.y * a.y + a.z * a.z + a.w * a.w
                + b.x * b.x + b.y * b.y + b.z * b.z + b.w * b.w;
        #pragma unroll
        for (int m = 16; m >= 1; m >>= 1) s += __shfl_xor(s, m, 64);
        if ((tid & 31) == 0) hen[base >> 8] = 0.5f * s;
        int gid = blk * 256 + tid;
        if (gid < K_CODES) cnt[gid] = 0u;
    }
}

// ---- 2. bf16 MFMA GEMM, 256x128 tile, 4 waves, 2-phase + high TLP -----------
// Round-0's proven 2-phase structure (stage -> sync -> compute, cross-block
// TLP hides everything) with geometry re-balanced for LDS bandwidth:
// per-wave tile 128x64 (WM*WN/(WM+WN) = 42.7 vs round-0's 25.6) -> 1.67x
// fewer LDS-read bytes per FLOP, 2x less staging per FLOP, half the blocks.
// LDS = 48 KB single-buffered; __launch_bounds__(256,3) -> 3 blocks/CU
// (12 waves/CU TLP). acc[8][4] = 128 VGPRs; expected total ~130 (round-2
// measured 120 with the same accumulator structure).
// Swizzle, de-swizzle, key packing, accumulation order (dc 0..3 x kk 0..1)
// and the wn-pair LDS merge are identical to the passing round-1/2 code;
// c1/c2 layout [64][16384] identical to round 0 -> downstream untouched.
__global__ __launch_bounds__(256, 3) void k_gemm(const short* __restrict__ zb,
                                                 const short* __restrict__ wb,
                                                 const float* __restrict__ hen,
                                                 unsigned* __restrict__ c1,
                                                 unsigned* __restrict__ c2) {
    __shared__ __align__(16) short As[256 * 64];   // 32 KB (256 z-rows x 64 k)
    __shared__ __align__(16) short Bs[128 * 64];   // 16 KB (128 codes x 64 k)

    const int tid  = threadIdx.x;
    const int lane = tid & 63;
    const int wv   = tid >> 6;              // 0..3
    const int wm   = wv >> 1;               // 0..1  (z half: 128 rows)
    const int wn   = wv & 1;                // 0..1  (code half: 64 cols)
    const int ztile = blockIdx.x & 63;      // consecutive blocks share B-tile
    const int kt    = blockIdx.x >> 6;      // 0..63 (= c-tile index, BN=128)
    const int z0 = ztile * 256, k0g = kt * 128;
    const int col = lane & 15;
    const int hi  = lane >> 4;
    const int x7  = lane & 7;

    f32x4 acc[8][4];
    #pragma unroll
    for (int ni = 0; ni < 4; ni++) {
        float h = 131072.0f - 128.0f * hen[k0g + wn * 64 + ni * 16 + col];
        f32x4 iv = {h, h, h, h};
        #pragma unroll
        for (int mi = 0; mi < 8; mi++) acc[mi][ni] = iv;
    }
    const unsigned invL = (unsigned)(K_CODES - 1 - (k0g + wn * 64 + col));

    // staging geometry: segments of 8 rows, 64 B/lane lines, XOR-swizzled
    const int sr    = lane >> 3;            // row within segment
    const int chunk = (lane & 7) ^ sr;      // pre-swizzled k-chunk
    const size_t abase = (size_t)(z0 + wv * 64 + sr) * DIM + chunk * 8;
    const size_t bbase = (size_t)(k0g + wv * 32 + sr) * DIM + chunk * 8;

    const int arow = (wm * 128 + col) * 64;   // + mi*1024 + s8 (shorts)
    const int brow = (wn * 64 + col) * 64;    // + ni*1024 + s8

    #pragma unroll 1
    for (int dc = 0; dc < 4; ++dc) {
        __syncthreads();
        // stage: A 8 segs/wave (32 total = 256 rows), B 4 segs/wave (128 rows)
        #pragma unroll
        for (int i = 0; i < 8; ++i)
            gload16(zb + abase + (size_t)i * 8 * DIM + dc * 64,
                    As + (wv * 8 + i) * 512 + lane * 8);
        #pragma unroll
        for (int i = 0; i < 4; ++i)
            gload16(wb + bbase + (size_t)i * 8 * DIM + dc * 64,
                    Bs + (wv * 4 + i) * 512 + lane * 8);
        __syncthreads();
        #pragma unroll
        for (int kk = 0; kk < 2; ++kk) {
            const int s8 = ((((kk << 2) + hi) ^ x7) << 3);
            bf16x8 b[4];
            #pragma unroll
            for (int ni = 0; ni < 4; ni++)
                b[ni] = *(const bf16x8*)&Bs[brow + ni * 1024 + s8];
            #pragma unroll
            for (int mi = 0; mi < 8; mi++) {
                bf16x8 a = *(const bf16x8*)&As[arow + mi * 1024 + s8];
                #pragma unroll
                for (int ni = 0; ni < 4; ni++)
                    acc[mi][ni] = __builtin_amdgcn_mfma_f32_16x16x32_bf16(
                        a, b[ni], acc[mi][ni], 0, 0, 0);
            }
        }
    }

    __syncthreads();   // all LDS reads done before overlaying merge buffer
    // epilogue: per-wave top-2 of its 64 codes per z-row (keys: q<<13 | invid)
    unsigned (*ldsT)[4] = (unsigned (*)[4])(&As[0]);   // 4 KB overlay
    #pragma unroll
    for (int mi = 0; mi < 8; mi++) {
        #pragma unroll
        for (int r = 0; r < 4; r++) {
            unsigned k4[4];
            #pragma unroll
            for (int ni = 0; ni < 4; ni++) {
                unsigned q = (unsigned)acc[mi][ni][r];
                k4[ni] = (q << 13) | (invL - 16u * ni);
            }
            unsigned p1 = umaxu(k4[0], k4[1]), q1 = uminu(k4[0], k4[1]);
            unsigned p2 = umaxu(k4[2], k4[3]), q2 = uminu(k4[2], k4[3]);
            unsigned t1 = umaxu(p1, p2);
            unsigned t2 = umaxu(uminu(p1, p2), umaxu(q1, q2));
            unsigned m1 = t1;
            #pragma unroll
            for (int m = 8; m >= 1; m >>= 1)
                m1 = umaxu(m1, (unsigned)__shfl_xor((int)m1, m, 64));
            unsigned cc = (t1 == m1) ? t2 : t1;     // keys unique (code id bits)
            #pragma unroll
            for (int m = 8; m >= 1; m >>= 1)
                cc = umaxu(cc, (unsigned)__shfl_xor((int)cc, m, 64));
            if (col == 0) {
                int rowl = wm * 128 + mi * 16 + hi * 4 + r;
                ldsT[rowl][wn * 2]     = m1;
                ldsT[rowl][wn * 2 + 1] = cc;
            }
        }
    }
    __syncthreads();
    // merge wn pair -> per-128-code-tile top-2 (identical c1/c2 semantics)
    {
        int row = tid;                      // 256 threads, 256 rows
        unsigned a0 = ldsT[row][0], a1 = ldsT[row][1];
        unsigned b0 = ldsT[row][2], b1 = ldsT[row][3];
        unsigned t1 = umaxu(a0, b0);
        unsigned t2 = umaxu(uminu(a0, b0), umaxu(a1, b1));
        size_t o = (size_t)kt * N_PTS + z0 + row;
        c1[o] = t1;
        c2[o] = t2;
    }
}

// ---- 3. rescore: idx + loss only (no z read, no z_q write, no fast-path w) --
// loss identity: ||z - w||^2 = ||z||^2 - 2*score. Fast path uses the quantized
// key score ((q - 131072)/128, error <= 1/128 + bf16 noise -> ~3e-5 on final
// mean loss). Slow path tracks the winner's fp32 score.
__global__ __launch_bounds__(1024) void k_rescore(
        const float* __restrict__ z, const float* __restrict__ w,
        const unsigned* __restrict__ c1, const unsigned* __restrict__ c2,
        const float* __restrict__ zn2,
        float* __restrict__ out,
        unsigned* __restrict__ cnt, float* __restrict__ lossp) {
    __shared__ unsigned s1[64 * 17], s2[64 * 17];   // 8.5 KB
    const int t  = threadIdx.x;
    const int w0 = blockIdx.x * 16;
    {
        int kt = t >> 4, wo = t & 15;               // 64-B line per 16 threads
        s1[kt * 17 + wo] = c1[(size_t)kt * N_PTS + w0 + wo];
        s2[kt * 17 + wo] = c2[(size_t)kt * N_PTS + w0 + wo];
    }
    __syncthreads();
    const int wv   = t >> 6;       // 0..15 -> wid
    const int lane = t & 63;       // = kt
    const int wid  = w0 + wv;
    unsigned k1 = s1[lane * 17 + wv];
    unsigned k2 = s2[lane * 17 + wv];

    // global best m1 and runner-up m2 over all 128 keys (k1 >= k2 per lane)
    unsigned m1 = k1;
    #pragma unroll
    for (int m = 32; m >= 1; m >>= 1)
        m1 = umaxu(m1, (unsigned)__shfl_xor((int)m1, m, 64));
    unsigned e = (k1 == m1) ? k2 : k1;
    unsigned m2 = e;
    #pragma unroll
    for (int m = 32; m >= 1; m >>= 1)
        m2 = umaxu(m2, (unsigned)__shfl_xor((int)m2, m, 64));

    int idx = K_CODES - 1 - (int)(m1 & 0x1FFFu);
    float scf = ((float)(int)(m1 >> 13) - 131072.0f) * 0.0078125f;

    unsigned qthr = (m1 >> 13) - 96u;     // 0.75 fp32-score window
    if ((m2 >> 13) >= qthr) {             // wave-uniform slow path (~20%)
        unsigned long long best = 0ULL;
        float bsc = 0.f;
        #pragma unroll
        for (int j = 0; j < 2; j++) {
            unsigned cj = j ? k2 : k1;
            unsigned long long mask = __ballot((cj >> 13) >= qthr);
            while (mask) {
                int l = __ffsll((unsigned long long)mask) - 1;
                mask &= mask - 1;
                unsigned cwd = (unsigned)__shfl((int)cj, l, 64);
                int k = K_CODES - 1 - (int)(cwd & 0x1FFFu);
                float4 wr = *(const float4*)(w + (size_t)k * DIM + lane * 4);
                float s = 0.f, h = 0.f;
                {
                    const float* zr = z + (size_t)wid * DIM + lane * 4;
                    float4 zv = *(const float4*)zr;
                    s = zv.x * wr.x + zv.y * wr.y + zv.z * wr.z + zv.w * wr.w;
                    h = wr.x * wr.x + wr.y * wr.y + wr.z * wr.z + wr.w * wr.w;
                }
                #pragma unroll
                for (int m = 32; m >= 1; m >>= 1) {
                    s += __shfl_xor(s, m, 64);
                    h += __shfl_xor(h, m, 64);
                }
                float sc = s - 0.5f * h;
                unsigned u = __float_as_uint(sc);
                u = (u & 0x80000000u) ? ~u : (u | 0x80000000u);
                unsigned long long key = ((unsigned long long)u << 32)
                                       | (unsigned)(K_CODES - 1 - k);
                bool better = key > best;             // wave-uniform
                best = better ? key : best;
                bsc  = better ? sc  : bsc;
            }
        }
        idx = K_CODES - 1 - (int)(unsigned)(best & 0xFFFFFFFFull);
        scf = bsc;
    }

    if (lane == 0) {
        out[OFF_IDX + wid] = (float)idx;
        lossp[wid] = zn2[wid] - 2.0f * scf;
        atomicAdd(cnt + idx, 1u);
    }
}

// ---- 4. single-block: scan + new_cs + n + loss + fill (cursor in LDS) -------
__global__ __launch_bounds__(1024) void k_prefix(const float* __restrict__ csin,
                                                 float* __restrict__ out,
                                                 const unsigned* __restrict__ cnt,
                                                 unsigned* __restrict__ offs,
                                                 unsigned* __restrict__ list,
                                                 const float* __restrict__ lossp,
                                                 float* __restrict__ nval) {
    __shared__ unsigned scur[K_CODES];     // 32 KB LDS cursor
    __shared__ unsigned wtot[16], wbase[16];
    __shared__ float fred[16], fred2[16];
    int t = threadIdx.x, lane = t & 63, wv = t >> 6;
    int base = t * 8;
    unsigned c[8], mysum = 0;
    #pragma unroll
    for (int i = 0; i < 8; i++) { c[i] = cnt[base + i]; mysum += c[i]; }
    unsigned inc = mysum;
    #pragma unroll
    for (int off = 1; off < 64; off <<= 1) {
        unsigned v = (unsigned)__shfl_up((int)inc, off, 64);
        if (lane >= off) inc += v;
    }
    if (lane == 63) wtot[wv] = inc;
    __syncthreads();
    if (t == 0) {
        unsigned r = 0;
        for (int i = 0; i < 16; i++) { wbase[i] = r; r += wtot[i]; }
        offs[K_CODES] = r;
    }
    __syncthreads();
    unsigned my0 = wbase[wv] + inc - mysum;
    float csl = 0.f;
    #pragma unroll
    for (int i = 0; i < 8; i++) {
        offs[base + i] = my0;
        scur[base + i] = my0;
        my0 += c[i];
        float ncs = DECAYF * csin[base + i] + OMDF * (float)c[i];
        out[OFF_CS + base + i] = ncs;
        csl += ncs;
    }
    #pragma unroll
    for (int m = 32; m >= 1; m >>= 1) csl += __shfl_xor(csl, m, 64);
    if (lane == 0) fred[wv] = csl;
    float lp = 0.f;
    #pragma unroll
    for (int i = 0; i < 16; i++) lp += lossp[t + i * 1024];
    #pragma unroll
    for (int m = 32; m >= 1; m >>= 1) lp += __shfl_xor(lp, m, 64);
    if (lane == 0) fred2[wv] = lp;
    __syncthreads();
    if (t == 0) {
        float n = 0.f, L = 0.f;
        for (int i = 0; i < 16; i++) { n += fred[i]; L += fred2[i]; }
        *nval = n;
        out[OFF_LOSS] = L * (1.0f / ((float)N_PTS * DIM));
    }
    // fill phase: LDS-atomic cursors, scattered list writes
    for (int i = t; i < N_PTS; i += 1024) {
        int idx = (int)out[OFF_IDX + i];
        unsigned pos = atomicAdd(&scur[idx], 1u);
        list[pos] = (unsigned)i;
    }
}

// ---- 5. per-code gather: z_q scatter + new_ea + new_weight (no atomics) -----
__global__ void k_gather(const float* __restrict__ z, const float* __restrict__ ea,
                         const float* __restrict__ w,
                         float* __restrict__ out,
                         const unsigned* __restrict__ offs,
                         const unsigned* __restrict__ list,
                         const float* __restrict__ nval) {
    int k = blockIdx.x, lane = threadIdx.x;
    unsigned beg = offs[k], end = offs[k + 1];
    float4 wv = *(const float4*)(w + (size_t)k * DIM + lane * 4);
    float4 acc = {0.f, 0.f, 0.f, 0.f};
    for (unsigned p = beg; p < end; ++p) {
        unsigned i = list[p];
        float4 zv = *(const float4*)(z + (size_t)i * DIM + lane * 4);
        acc.x += zv.x; acc.y += zv.y; acc.z += zv.z; acc.w += zv.w;
        *(float4*)(out + OFF_ZQ + (size_t)i * DIM + lane * 4) = wv;  // z_q = w[idx]
    }
    float4 e = *(const float4*)(ea + (size_t)k * DIM + lane * 4);
    e.x = DECAYF * e.x + OMDF * acc.x;
    e.y = DECAYF * e.y + OMDF * acc.y;
    e.z = DECAYF * e.z + OMDF * acc.z;
    e.w = DECAYF * e.w + OMDF * acc.w;
    *(float4*)(out + OFF_EA + (size_t)k * DIM + lane * 4) = e;

    float cs = out[OFF_CS + k];
    float n  = *nval;
    float inv = 1.f / ((cs + EPSF) / (n + (float)K_CODES * EPSF) * n);
    float4 wr = {e.x * inv, e.y * inv, e.z * inv, e.w * inv};
    *(float4*)(out + OFF_W + (size_t)k * DIM + lane * 4) = wr;
}

extern "C" void kernel_launch(void* const* d_in, const int* in_sizes, int n_in,
                              void* d_out, int out_size, void* d_ws, size_t ws_size,
                              hipStream_t stream) {
    const float* z  = (const float*)d_in[0];
    const float* w  = (const float*)d_in[1];
    const float* cs = (const float*)d_in[2];
    const float* ea = (const float*)d_in[3];
    float* out = (float*)d_out;

    short*    zb  = (short*)(out + ZB_OFF);
    short*    wb  = (short*)(out + WB_OFF);
    float*    hen = out + HEN_OFF;
    unsigned* c1  = (unsigned*)(out + C1_OFF);
    unsigned* c2  = (unsigned*)(out + C2_OFF);

    // small scratch in d_ws (~262 KB)
    unsigned* cnt   = (unsigned*)d_ws;        // 8192
    unsigned* offs  = cnt + 8192;             // 8193 (padded to 8200)
    unsigned* list  = offs + 8200;            // 16384
    float*    lossp = (float*)(list + 16384); // 16384
    float*    nval  = lossp + 16384;          // 1
    float*    zn2   = nval + 1;               // 16384

    hipLaunchKernelGGL(k_cvt2,    dim3((N_PTS + K_CODES) * DIM / 2048), dim3(256), 0, stream,
                       z, zb, w, wb, hen, cnt, zn2);
    hipLaunchKernelGGL(k_gemm,    dim3((N_PTS / 256) * (K_CODES / 128)), dim3(256), 0, stream,
                       zb, wb, hen, c1, c2);
    hipLaunchKernelGGL(k_rescore, dim3(N_PTS / 16),           dim3(1024), 0, stream,
                       z, w, c1, c2, zn2, out, cnt, lossp);
    hipLaunchKernelGGL(k_prefix,  dim3(1),                    dim3(1024), 0, stream,
                       cs, out, cnt, offs, list, lossp, nval);
    hipLaunchKernelGGL(k_gather,  dim3(K_CODES),              dim3(64), 0, stream,
                       z, ea, w, out, offs, list, nval);
}